// Round 4
// baseline (592.934 us; speedup 1.0000x reference)
//
#include <hip/hip_runtime.h>

#define TSTEPS 128
#define NIN 24
#define HD 128
#define BT 16
#define NTILES 128     // 2048 / BT batch tiles
#define NTH 512

// LDS geometry (units: _Float16 elements)
#define RS    136               // h-panel row stride (272 B, 16B-aligned)
#define SLOT  (BT*RS)           // 2176
#define XS    40                // x row stride (cols 0..23 x, 24..39 zero)
#define XTS   (BT*XS)           // 640
#define XCH   8                 // steps per x chunk
#define XBUF  (XCH*XTS)         // 5120

// producer overlay: 8-slot h1 ring + x double buffer
#define RING_OFF 0
#define XB_OFF   (8*SLOT)               // 17408
#define SM_SIZE  (XB_OFF + 2*XBUF)      // 27648 f16 = 55296 B

// consumer overlay: h1 chunk dbuf (2 x 4 slots) + h2 dbuf (2 slots)
#define HB_OFF 0                        // 8*SLOT = 17408
#define H2_OFF (8*SLOT)                 // +2*SLOT = 21760 total (< SM_SIZE)

#define WS_DATA_F16 ((size_t)NTILES * TSTEPS * BT * HD)   // 33554432 f16 = 64 MB

typedef _Float16 half8  __attribute__((ext_vector_type(8)));
typedef _Float16 half4v __attribute__((ext_vector_type(4)));
typedef float    floatx4 __attribute__((ext_vector_type(4)));

__device__ __forceinline__ float sigf(float x) {
    return __builtin_amdgcn_rcpf(1.0f + __expf(-x));
}
__device__ __forceinline__ float tanh_f(float x) {
    return 1.0f - 2.0f * __builtin_amdgcn_rcpf(1.0f + __expf(2.0f * x));
}

__device__ __forceinline__ half8 ldw8(const float* p) {
    const float4* q = (const float4*)p;
    float4 a = q[0], b = q[1];
    half8 r;
    r[0] = (_Float16)a.x; r[1] = (_Float16)a.y; r[2] = (_Float16)a.z; r[3] = (_Float16)a.w;
    r[4] = (_Float16)b.x; r[5] = (_Float16)b.y; r[6] = (_Float16)b.z; r[7] = (_Float16)b.w;
    return r;
}

__global__ __launch_bounds__(NTH, 2)
void lstm2_pc(const float* __restrict__ x,
              const float* __restrict__ Wih0, const float* __restrict__ Whh0,
              const float* __restrict__ bih0, const float* __restrict__ bhh0,
              const float* __restrict__ Wih1, const float* __restrict__ Whh1,
              const float* __restrict__ bih1, const float* __restrict__ bhh1,
              const float* __restrict__ Wfc,  const float* __restrict__ bfc,
              float* __restrict__ out, _Float16* __restrict__ h1ws, int* __restrict__ flags)
{
    __shared__ __align__(16) _Float16 SM[SM_SIZE];

    const int tid = threadIdx.x;
    const int wv  = tid >> 6;
    const int ln  = tid & 63;
    const int qd  = ln >> 4;
    const int nn  = ln & 15;
    const int jc  = wv * 16 + nn;
    const half8 z8 = {0, 0, 0, 0, 0, 0, 0, 0};

    if (blockIdx.x < NTILES) {
        // ================= PRODUCER: layer 0 for batch tile p =================
        const int p = blockIdx.x;
        const int b0 = p * BT;
        const size_t wsp = (size_t)p * (TSTEPS * BT * HD);

        // zero ring (h1_{-1}=0) and x buffers (pad cols stay 0)
        for (int i = tid * 8; i < SM_SIZE; i += NTH * 8) *(half8*)&SM[i] = z8;

        half8 wih0[4];
        half8 whh0[4][4];
        float bias0[4];
#pragma unroll
        for (int tI = 0; tI < 4; ++tI) {
            int g = tI * HD + jc;
            bias0[tI] = bih0[g] + bhh0[g];
            if (qd < 3) wih0[tI] = ldw8(Wih0 + g * NIN + qd * 8);
            else        wih0[tI] = z8;
#pragma unroll
            for (int kk = 0; kk < 4; ++kk)
                whh0[tI][kk] = ldw8(Whh0 + g * HD + kk * 32 + qd * 8);
        }

        __syncthreads();   // zero-init visible

        // stage x chunk 0 (steps 0..7)
        for (int i = tid; i < XCH * BT * 6; i += NTH) {
            int ti = i / 96, r = i % 96, b = r / 6, q = r % 6;
            float4 v = *(const float4*)(x + (size_t)(b0 + b) * (TSTEPS * NIN) + ti * NIN + q * 4);
            half4v h; h[0] = (_Float16)v.x; h[1] = (_Float16)v.y;
                      h[2] = (_Float16)v.z; h[3] = (_Float16)v.w;
            *(half4v*)&SM[XB_OFF + ti * XTS + b * XS + q * 4] = h;
        }

        float cs0[4] = {0.f, 0.f, 0.f, 0.f};

#pragma unroll 1
        for (int t = 0; t < TSTEPS; ++t) {
            __syncthreads();     // prev epilogue + staging visible; vmcnt drained

            // release flag for chunk dumped last iteration (stores drained by barrier)
            if ((t & 3) == 1 && t >= 5 && tid == 0) {
                int c = (t - 5) >> 2;
                __threadfence();
                __hip_atomic_store(&flags[p * 32 + c], c + 1,
                                   __ATOMIC_RELEASE, __HIP_MEMORY_SCOPE_AGENT);
            }

            // stage x chunk t/8+1
            if ((t & 7) == 0 && t + XCH < TSTEPS) {
                const int c = (t >> 3) + 1, buf = c & 1;
                for (int i = tid; i < XCH * BT * 6; i += NTH) {
                    int ti = i / 96, r = i % 96, b = r / 6, q = r % 6;
                    float4 v = *(const float4*)(x + (size_t)(b0 + b) * (TSTEPS * NIN)
                                                  + (size_t)(c * XCH + ti) * NIN + q * 4);
                    half4v h; h[0] = (_Float16)v.x; h[1] = (_Float16)v.y;
                              h[2] = (_Float16)v.z; h[3] = (_Float16)v.w;
                    *(half4v*)&SM[XB_OFF + buf * XBUF + ti * XTS + b * XS + q * 4] = h;
                }
            }
            // dump chunk t/4-1 (steps t-4..t-1) to workspace
            if ((t & 3) == 0 && t > 0) {
#pragma unroll
                for (int k = 0; k < 2; ++k) {
                    int e  = tid + k * NTH;          // 0..1023
                    int ti = e >> 8;
                    int r  = e & 255;
                    int b  = r >> 4;
                    int c8 = (r & 15) * 8;
                    int tau = t - 4 + ti;
                    half8 v = *(const half8*)&SM[RING_OFF + (tau & 7) * SLOT + b * RS + c8];
                    *(half8*)(h1ws + wsp + ((size_t)tau * BT + b) * HD + c8) = v;
                }
            }

            // ---- step t compute ----
            const half8 ax = *(const half8*)&SM[XB_OFF + ((t >> 3) & 1) * XBUF
                                                + (t & 7) * XTS + nn * XS + qd * 8];
            half8 ah[4];
#pragma unroll
            for (int kk = 0; kk < 4; ++kk)
                ah[kk] = *(const half8*)&SM[RING_OFF + ((t - 1) & 7) * SLOT + nn * RS + kk * 32 + qd * 8];

            floatx4 acc[4];
#pragma unroll
            for (int tI = 0; tI < 4; ++tI) {
                floatx4 a = {bias0[tI], bias0[tI], bias0[tI], bias0[tI]};
                a = __builtin_amdgcn_mfma_f32_16x16x32_f16(ax, wih0[tI], a, 0, 0, 0);
#pragma unroll
                for (int kk = 0; kk < 4; ++kk)
                    a = __builtin_amdgcn_mfma_f32_16x16x32_f16(ah[kk], whh0[tI][kk], a, 0, 0, 0);
                acc[tI] = a;
            }
#pragma unroll
            for (int r = 0; r < 4; ++r) {
                float iv = sigf(acc[0][r]);
                float fv = sigf(acc[1][r]);
                float gv = tanh_f(acc[2][r]);
                float ov = sigf(acc[3][r]);
                float cn = fv * cs0[r] + iv * gv;
                cs0[r] = cn;
                float hv = ov * tanh_f(cn);
                SM[RING_OFF + (t & 7) * SLOT + (qd * 4 + r) * RS + jc] = (_Float16)hv;
            }
        }

        __syncthreads();
        // dump final chunk 31 (steps 124..127)
#pragma unroll
        for (int k = 0; k < 2; ++k) {
            int e  = tid + k * NTH;
            int ti = e >> 8;
            int r  = e & 255;
            int b  = r >> 4;
            int c8 = (r & 15) * 8;
            int tau = 124 + ti;
            half8 v = *(const half8*)&SM[RING_OFF + (tau & 7) * SLOT + b * RS + c8];
            *(half8*)(h1ws + wsp + ((size_t)tau * BT + b) * HD + c8) = v;
        }
        __syncthreads();   // drain all waves' stores
        if (tid == 0) {
            __threadfence();
            __hip_atomic_store(&flags[p * 32 + 31], 32,
                               __ATOMIC_RELEASE, __HIP_MEMORY_SCOPE_AGENT);
        }
    } else {
        // ================= CONSUMER: layer 1 + FC for batch tile p =================
        const int p = blockIdx.x - NTILES;
        const size_t wsp = (size_t)p * (TSTEPS * BT * HD);

        half8 w1[4][8];
        float bias1[4];
#pragma unroll
        for (int tI = 0; tI < 4; ++tI) {
            int g = tI * HD + jc;
            bias1[tI] = bih1[g] + bhh1[g];
#pragma unroll
            for (int kk = 0; kk < 4; ++kk) {
                w1[tI][kk]     = ldw8(Wih1 + g * HD + kk * 32 + qd * 8);
                w1[tI][4 + kk] = ldw8(Whh1 + g * HD + kk * 32 + qd * 8);
            }
        }
        // zero h2 slots
        for (int i = tid * 8; i < 2 * SLOT; i += NTH * 8) *(half8*)&SM[H2_OFF + i] = z8;

        // acquire + load chunk 0
        while (__hip_atomic_load(&flags[p * 32 + 0], __ATOMIC_ACQUIRE,
                                 __HIP_MEMORY_SCOPE_AGENT) != 1) {}
#pragma unroll
        for (int k = 0; k < 2; ++k) {
            int e  = tid + k * NTH;
            int ti = e >> 8;
            int r  = e & 255;
            int b  = r >> 4;
            int c8 = (r & 15) * 8;
            half8 v = *(const half8*)(h1ws + wsp + ((size_t)ti * BT + b) * HD + c8);
            *(half8*)&SM[HB_OFF + ti * SLOT + b * RS + c8] = v;
        }

        float cs1[4] = {0.f, 0.f, 0.f, 0.f};

#pragma unroll 1
        for (int tau = 0; tau < TSTEPS; ++tau) {
            __syncthreads();

            // acquire + load next chunk (double-buffered)
            if ((tau & 3) == 0 && tau + 4 < TSTEPS) {
                const int c = (tau >> 2) + 1, buf = c & 1;
                while (__hip_atomic_load(&flags[p * 32 + c], __ATOMIC_ACQUIRE,
                                         __HIP_MEMORY_SCOPE_AGENT) != c + 1) {}
#pragma unroll
                for (int k = 0; k < 2; ++k) {
                    int e  = tid + k * NTH;
                    int ti = e >> 8;
                    int r  = e & 255;
                    int b  = r >> 4;
                    int c8 = (r & 15) * 8;
                    half8 v = *(const half8*)(h1ws + wsp + ((size_t)(c * 4 + ti) * BT + b) * HD + c8);
                    *(half8*)&SM[HB_OFF + buf * (4 * SLOT) + ti * SLOT + b * RS + c8] = v;
                }
            }

            const int hbase = HB_OFF + ((tau >> 2) & 1) * (4 * SLOT) + (tau & 3) * SLOT;
            half8 a1[4], a2[4];
#pragma unroll
            for (int kk = 0; kk < 4; ++kk) {
                a1[kk] = *(const half8*)&SM[hbase + nn * RS + kk * 32 + qd * 8];
                a2[kk] = *(const half8*)&SM[H2_OFF + (tau & 1) * SLOT + nn * RS + kk * 32 + qd * 8];
            }

            floatx4 acc[4];
#pragma unroll
            for (int tI = 0; tI < 4; ++tI) {
                floatx4 a = {bias1[tI], bias1[tI], bias1[tI], bias1[tI]};
#pragma unroll
                for (int kk = 0; kk < 4; ++kk)
                    a = __builtin_amdgcn_mfma_f32_16x16x32_f16(a1[kk], w1[tI][kk], a, 0, 0, 0);
#pragma unroll
                for (int kk = 0; kk < 4; ++kk)
                    a = __builtin_amdgcn_mfma_f32_16x16x32_f16(a2[kk], w1[tI][4 + kk], a, 0, 0, 0);
                acc[tI] = a;
            }

            const int wp = (tau & 1) ^ 1;
#pragma unroll
            for (int r = 0; r < 4; ++r) {
                float iv = sigf(acc[0][r]);
                float fv = sigf(acc[1][r]);
                float gv = tanh_f(acc[2][r]);
                float ov = sigf(acc[3][r]);
                float cn = fv * cs1[r] + iv * gv;
                cs1[r] = cn;
                float hv = ov * tanh_f(cn);
                SM[H2_OFF + wp * SLOT + (qd * 4 + r) * RS + jc] = (_Float16)hv;
            }
        }
        __syncthreads();

        // FC head: h2_127 in H2 slot 0
        {
            int b = tid >> 5, sub = tid & 31;
            const _Float16* hp = &SM[H2_OFF + b * RS + sub * 4];
            const float4 wv4 = *(const float4*)(Wfc + sub * 4);
            float s = (float)hp[0] * wv4.x + (float)hp[1] * wv4.y
                    + (float)hp[2] * wv4.z + (float)hp[3] * wv4.w;
            s += __shfl_down(s, 16, 32);
            s += __shfl_down(s, 8, 32);
            s += __shfl_down(s, 4, 32);
            s += __shfl_down(s, 2, 32);
            s += __shfl_down(s, 1, 32);
            if (sub == 0) out[p * BT + b] = s + bfc[0];
        }
    }
}

extern "C" void kernel_launch(void* const* d_in, const int* in_sizes, int n_in,
                              void* d_out, int out_size, void* d_ws, size_t ws_size,
                              hipStream_t stream) {
    const float* x    = (const float*)d_in[0];
    const float* Wih0 = (const float*)d_in[1];
    const float* Whh0 = (const float*)d_in[2];
    const float* bih0 = (const float*)d_in[3];
    const float* bhh0 = (const float*)d_in[4];
    const float* Wih1 = (const float*)d_in[5];
    const float* Whh1 = (const float*)d_in[6];
    const float* bih1 = (const float*)d_in[7];
    const float* bhh1 = (const float*)d_in[8];
    const float* Wfc  = (const float*)d_in[9];
    const float* bfc  = (const float*)d_in[10];
    float* out = (float*)d_out;
    _Float16* h1ws = (_Float16*)d_ws;                      // 64 MB data
    int* flags = (int*)((char*)d_ws + WS_DATA_F16 * 2);    // +16 KB flags (poison-safe)

    lstm2_pc<<<dim3(2 * NTILES), dim3(NTH), 0, stream>>>(
        x, Wih0, Whh0, bih0, bhh0, Wih1, Whh1, bih1, bhh1, Wfc, bfc, out, h1ws, flags);
}

// Round 5
// 474.118 us; speedup vs baseline: 1.2506x; 1.2506x over previous
//
#include <hip/hip_runtime.h>

#define TSTEPS 128
#define NIN 24
#define HD 128
#define BT 16
#define NBLK 128     // 2048 / BT
#define NTH 512

// LDS geometry (units: _Float16 elements)
#define RS    136               // h-panel row stride (272 B: 16B-aligned)
#define SLOT  (BT*RS)           // 2176
#define XS    40                // x row stride (cols 0..23 x, col 24 = 1.0 bias hook, rest 0)
#define XTS   (BT*XS)           // 640 per timestep
#define XCH   4                 // steps per x chunk
#define XBUF  (XCH*XTS)         // 2560

#define WIH0_OFF 0                      // frag table: 4 tI * 8 wv * 64 ln * 8 f16 = 16384
#define H1_OFF   16384                  // 2 slots
#define H2_OFF   (H1_OFF + 2*SLOT)     // 20736
#define XB_OFF   (H2_OFF + 2*SLOT)     // 25088
#define SM_SIZE  (XB_OFF + 2*XBUF)     // 30208 f16 = 60416 B

typedef _Float16 half8  __attribute__((ext_vector_type(8)));
typedef _Float16 half4v __attribute__((ext_vector_type(4)));
typedef float    floatx4 __attribute__((ext_vector_type(4)));

__device__ __forceinline__ float sigf(float x) {
    return __builtin_amdgcn_rcpf(1.0f + __expf(-x));
}
__device__ __forceinline__ float tanh_f(float x) {
    return 1.0f - 2.0f * __builtin_amdgcn_rcpf(1.0f + __expf(2.0f * x));
}

__device__ __forceinline__ half8 ldw8(const float* p) {
    const float4* q = (const float4*)p;
    float4 a = q[0], b = q[1];
    half8 r;
    r[0] = (_Float16)a.x; r[1] = (_Float16)a.y; r[2] = (_Float16)a.z; r[3] = (_Float16)a.w;
    r[4] = (_Float16)b.x; r[5] = (_Float16)b.y; r[6] = (_Float16)b.z; r[7] = (_Float16)b.w;
    return r;
}

// waves_per_eu(2,2): grid=128 gives exactly 1 block (8 waves) per CU = 2 waves/EU.
// Tell the allocator so it budgets 256 VGPR/wave instead of squeezing to 128 and
// spilling the 192 resident weight VGPRs (R3: 45.8 MB scratch writes in the hot loop).
__global__ __launch_bounds__(NTH)
__attribute__((amdgpu_waves_per_eu(2, 2)))
void lstm2_il(const float* __restrict__ x,
              const float* __restrict__ Wih0, const float* __restrict__ Whh0,
              const float* __restrict__ bih0, const float* __restrict__ bhh0,
              const float* __restrict__ Wih1, const float* __restrict__ Whh1,
              const float* __restrict__ bih1, const float* __restrict__ bhh1,
              const float* __restrict__ Wfc,  const float* __restrict__ bfc,
              float* __restrict__ out)
{
    __shared__ __align__(16) _Float16 SM[SM_SIZE];

    const int tid = threadIdx.x;
    const int blk = blockIdx.x;
    const int wv  = tid >> 6;
    const int ln  = tid & 63;
    const int qd  = ln >> 4;
    const int nn  = ln & 15;
    const int b0  = blk * BT;
    const int jc  = wv * 16 + nn;       // this lane's h/gate column

    const half8 z8 = {0, 0, 0, 0, 0, 0, 0, 0};

    // ---- zero all LDS (h slots = initial h=0; x pad cols stay 0) ----
    for (int i = tid * 8; i < SM_SIZE; i += NTH * 8) *(half8*)&SM[i] = z8;

    // ---- resident weights: whh0 (64 VGPR) + w1 (128 VGPR) ----
    half8 whh0[4][4];
    half8 w1[4][8];
    float bias1[4];
#pragma unroll
    for (int tI = 0; tI < 4; ++tI) {
        int g = tI * HD + wv * 16 + nn;
        bias1[tI] = bih1[g] + bhh1[g];
#pragma unroll
        for (int kk = 0; kk < 4; ++kk) {
            whh0[tI][kk] = ldw8(Whh0 + g * HD + kk * 32 + qd * 8);
            w1[tI][kk]     = ldw8(Wih1 + g * HD + kk * 32 + qd * 8);
            w1[tI][4 + kk] = ldw8(Whh1 + g * HD + kk * 32 + qd * 8);
        }
    }

    // ---- wih0 frag table into LDS (bias0 folded into K-row 24 via x col24=1.0) ----
    for (int e = tid; e < 2048; e += NTH) {
        int tI2 = e >> 9, wv2 = (e >> 6) & 7, ln2 = e & 63;
        int qd2 = ln2 >> 4, nn2 = ln2 & 15;
        int g = tI2 * HD + wv2 * 16 + nn2;
        half8 f = z8;
        if (qd2 < 3) f = ldw8(Wih0 + g * NIN + qd2 * 8);
        else         f[0] = (_Float16)(bih0[g] + bhh0[g]);   // K-row 24
        *(half8*)&SM[WIH0_OFF + e * 8] = f;
    }

    __syncthreads();   // zero-init + wih0 table visible

    // ---- stage x chunk 0 (steps 0..3) into buf 0 ----
    if (tid < XCH * BT * 7) {
        int ti = tid / 112, r = tid % 112, b = r / 7, q = r % 7;
        half4v h;
        if (q < 6) {
            float4 v = *(const float4*)(x + (size_t)(b0 + b) * (TSTEPS * NIN) + ti * NIN + q * 4);
            h[0] = (_Float16)v.x; h[1] = (_Float16)v.y; h[2] = (_Float16)v.z; h[3] = (_Float16)v.w;
        } else {
            h[0] = (_Float16)1.f; h[1] = 0; h[2] = 0; h[3] = 0;   // col 24 = 1.0 (bias hook)
        }
        *(half4v*)&SM[XB_OFF + ti * XTS + b * XS + q * 4] = h;
    }

    float cs0[4] = {0.f, 0.f, 0.f, 0.f};
    float cs1[4] = {0.f, 0.f, 0.f, 0.f};

    // ====== fused loop: iteration t = L0 step t + L1 step t-1 ======
#pragma unroll 1
    for (int t = 0; t <= TSTEPS; ++t) {
        __syncthreads();

        // stage x chunk t/XCH + 1 (for steps t+4..t+7)
        if (t < TSTEPS && (t & (XCH - 1)) == 0 && t + XCH < TSTEPS) {
            const int c = (t >> 2) + 1, buf = c & 1;
            if (tid < XCH * BT * 7) {
                int ti = tid / 112, r = tid % 112, b = r / 7, q = r % 7;
                half4v h;
                if (q < 6) {
                    float4 v = *(const float4*)(x + (size_t)(b0 + b) * (TSTEPS * NIN)
                                                  + (size_t)(c * XCH + ti) * NIN + q * 4);
                    h[0] = (_Float16)v.x; h[1] = (_Float16)v.y;
                    h[2] = (_Float16)v.z; h[3] = (_Float16)v.w;
                } else {
                    h[0] = (_Float16)1.f; h[1] = 0; h[2] = 0; h[3] = 0;
                }
                *(half4v*)&SM[XB_OFF + buf * XBUF + ti * XTS + b * XS + q * 4] = h;
            }
        }

        // -------- layer 0, step t --------
        if (t < TSTEPS) {
            const half8 ax = *(const half8*)&SM[XB_OFF + ((t >> 2) & 1) * XBUF
                                                + (t & (XCH - 1)) * XTS + nn * XS + qd * 8];
            floatx4 acc[4];
#pragma unroll
            for (int tI = 0; tI < 4; ++tI) {
                const half8 wf = *(const half8*)&SM[WIH0_OFF + ((tI * 8 + wv) * 64 + ln) * 8];
                floatx4 a = {0.f, 0.f, 0.f, 0.f};
                acc[tI] = __builtin_amdgcn_mfma_f32_16x16x32_f16(ax, wf, a, 0, 0, 0);
            }
            const int rp = (t & 1) ^ 1;      // h1_{t-1} slot
            half8 ah[4];
#pragma unroll
            for (int kk = 0; kk < 4; ++kk)
                ah[kk] = *(const half8*)&SM[H1_OFF + rp * SLOT + nn * RS + kk * 32 + qd * 8];
#pragma unroll
            for (int tI = 0; tI < 4; ++tI) {
#pragma unroll
                for (int kk = 0; kk < 4; ++kk)
                    acc[tI] = __builtin_amdgcn_mfma_f32_16x16x32_f16(ah[kk], whh0[tI][kk], acc[tI], 0, 0, 0);
            }
            const int wp = t & 1;            // h1_t slot
#pragma unroll
            for (int r = 0; r < 4; ++r) {
                float iv = sigf(acc[0][r]);
                float fv = sigf(acc[1][r]);
                float gv = tanh_f(acc[2][r]);
                float ov = sigf(acc[3][r]);
                float cn = fv * cs0[r] + iv * gv;
                cs0[r] = cn;
                float hv = ov * tanh_f(cn);
                SM[H1_OFF + wp * SLOT + (qd * 4 + r) * RS + jc] = (_Float16)hv;
            }
        }

        // -------- layer 1, step t-1 --------
        if (t >= 1) {
            const int rp = (t & 1) ^ 1;      // h1_{t-1} slot (and h2_{t-2} is slot t&1)
            floatx4 acc[4];
#pragma unroll
            for (int tI = 0; tI < 4; ++tI) {
                floatx4 a = {bias1[tI], bias1[tI], bias1[tI], bias1[tI]};
                acc[tI] = a;
            }
            half8 a1[4];
#pragma unroll
            for (int kk = 0; kk < 4; ++kk)
                a1[kk] = *(const half8*)&SM[H1_OFF + rp * SLOT + nn * RS + kk * 32 + qd * 8];
#pragma unroll
            for (int tI = 0; tI < 4; ++tI) {
#pragma unroll
                for (int kk = 0; kk < 4; ++kk)
                    acc[tI] = __builtin_amdgcn_mfma_f32_16x16x32_f16(a1[kk], w1[tI][kk], acc[tI], 0, 0, 0);
            }
            half8 a2[4];
#pragma unroll
            for (int kk = 0; kk < 4; ++kk)
                a2[kk] = *(const half8*)&SM[H2_OFF + (t & 1) * SLOT + nn * RS + kk * 32 + qd * 8];
#pragma unroll
            for (int tI = 0; tI < 4; ++tI) {
#pragma unroll
                for (int kk = 0; kk < 4; ++kk)
                    acc[tI] = __builtin_amdgcn_mfma_f32_16x16x32_f16(a2[kk], w1[tI][4 + kk], acc[tI], 0, 0, 0);
            }
            const int wp = (t & 1) ^ 1;      // h2_{t-1} slot
#pragma unroll
            for (int r = 0; r < 4; ++r) {
                float iv = sigf(acc[0][r]);
                float fv = sigf(acc[1][r]);
                float gv = tanh_f(acc[2][r]);
                float ov = sigf(acc[3][r]);
                float cn = fv * cs1[r] + iv * gv;
                cs1[r] = cn;
                float hv = ov * tanh_f(cn);
                SM[H2_OFF + wp * SLOT + (qd * 4 + r) * RS + jc] = (_Float16)hv;
            }
        }
    }
    __syncthreads();

    // ====== FC head: h2_127 is in H2 slot 1 ======
    {
        int b = tid >> 5, sub = tid & 31;
        const _Float16* hp = &SM[H2_OFF + SLOT + b * RS + sub * 4];
        const float4 wv4 = *(const float4*)(Wfc + sub * 4);
        float s = (float)hp[0] * wv4.x + (float)hp[1] * wv4.y
                + (float)hp[2] * wv4.z + (float)hp[3] * wv4.w;
        s += __shfl_down(s, 16, 32);
        s += __shfl_down(s, 8, 32);
        s += __shfl_down(s, 4, 32);
        s += __shfl_down(s, 2, 32);
        s += __shfl_down(s, 1, 32);
        if (sub == 0) out[b0 + b] = s + bfc[0];
    }
}

extern "C" void kernel_launch(void* const* d_in, const int* in_sizes, int n_in,
                              void* d_out, int out_size, void* d_ws, size_t ws_size,
                              hipStream_t stream) {
    const float* x    = (const float*)d_in[0];
    const float* Wih0 = (const float*)d_in[1];
    const float* Whh0 = (const float*)d_in[2];
    const float* bih0 = (const float*)d_in[3];
    const float* bhh0 = (const float*)d_in[4];
    const float* Wih1 = (const float*)d_in[5];
    const float* Whh1 = (const float*)d_in[6];
    const float* bih1 = (const float*)d_in[7];
    const float* bhh1 = (const float*)d_in[8];
    const float* Wfc  = (const float*)d_in[9];
    const float* bfc  = (const float*)d_in[10];
    float* out = (float*)d_out;

    lstm2_il<<<dim3(NBLK), dim3(NTH), 0, stream>>>(
        x, Wih0, Whh0, bih0, bhh0, Wih1, Whh1, bih1, bhh1, Wfc, bfc, out);
}

// Round 6
// 392.450 us; speedup vs baseline: 1.5109x; 1.2081x over previous
//
#include <hip/hip_runtime.h>

#define TSTEPS 128
#define NIN 24
#define HD 128
#define BT 16
#define NBLK 128     // 2048 / BT
#define NTH 512

// LDS geometry (units: _Float16 elements)
#define RS    136               // h-panel row stride (272 B: 16B-aligned)
#define SLOT  (BT*RS)           // 2176
#define XS    40                // x row stride (cols 0..23 x, col 24 = 1.0 bias hook, rest 0)
#define XTS   (BT*XS)           // 640 per timestep
#define XCH   4                 // steps per x chunk
#define XBUF  (XCH*XTS)         // 2560

#define WIH0_OFF 0                      // frag table: 4 tI * 8 wv * 64 ln * 8 f16 = 16384
#define H1_OFF   16384                  // 2 slots
#define H2_OFF   (H1_OFF + 2*SLOT)     // 20736
#define XB_OFF   (H2_OFF + 2*SLOT)     // 25088
#define SM_SIZE  (XB_OFF + 2*XBUF)     // 30208 f16 = 60416 B

typedef _Float16 half8  __attribute__((ext_vector_type(8)));
typedef _Float16 half4v __attribute__((ext_vector_type(4)));
typedef float    floatx4 __attribute__((ext_vector_type(4)));

__device__ __forceinline__ float sigf(float x) {
    return __builtin_amdgcn_rcpf(1.0f + __expf(-x));
}
__device__ __forceinline__ float tanh_f(float x) {
    return 1.0f - 2.0f * __builtin_amdgcn_rcpf(1.0f + __expf(2.0f * x));
}

__device__ __forceinline__ half8 ldw8(const float* p) {
    const float4* q = (const float4*)p;
    float4 a = q[0], b = q[1];
    half8 r;
    r[0] = (_Float16)a.x; r[1] = (_Float16)a.y; r[2] = (_Float16)a.z; r[3] = (_Float16)a.w;
    r[4] = (_Float16)b.x; r[5] = (_Float16)b.y; r[6] = (_Float16)b.z; r[7] = (_Float16)b.w;
    return r;
}

// Register budget note: unified VGPR+AGPR file = 256/wave at 8 waves/block.
// Resident weights 192 (whh0 64 + w1 128, allocator may place in AGPRs) +
// one acc bank 16 (reused by both layers) + streamed frags 8 + misc ~25 ≈ 241.
// R3 kept both acc banks + full frag arrays live (~272) -> 46 MB scratch spill.
__global__ __launch_bounds__(NTH, 2)
void lstm2_il(const float* __restrict__ x,
              const float* __restrict__ Wih0, const float* __restrict__ Whh0,
              const float* __restrict__ bih0, const float* __restrict__ bhh0,
              const float* __restrict__ Wih1, const float* __restrict__ Whh1,
              const float* __restrict__ bih1, const float* __restrict__ bhh1,
              const float* __restrict__ Wfc,  const float* __restrict__ bfc,
              float* __restrict__ out)
{
    __shared__ __align__(16) _Float16 SM[SM_SIZE];

    const int tid = threadIdx.x;
    const int blk = blockIdx.x;
    const int wv  = tid >> 6;
    const int ln  = tid & 63;
    const int qd  = ln >> 4;
    const int nn  = ln & 15;
    const int b0  = blk * BT;
    const int jc  = wv * 16 + nn;       // this lane's h/gate column

    const half8 z8 = {0, 0, 0, 0, 0, 0, 0, 0};

    // ---- zero all LDS (h slots = initial h=0; x pad cols stay 0) ----
    for (int i = tid * 8; i < SM_SIZE; i += NTH * 8) *(half8*)&SM[i] = z8;

    // ---- resident weights: whh0 (64 regs) + w1 (128 regs) ----
    half8 whh0[4][4];
    half8 w1[4][8];
    float bias1[4];
#pragma unroll
    for (int tI = 0; tI < 4; ++tI) {
        int g = tI * HD + jc;
        bias1[tI] = bih1[g] + bhh1[g];
#pragma unroll
        for (int kk = 0; kk < 4; ++kk) {
            whh0[tI][kk] = ldw8(Whh0 + g * HD + kk * 32 + qd * 8);
            w1[tI][kk]     = ldw8(Wih1 + g * HD + kk * 32 + qd * 8);
            w1[tI][4 + kk] = ldw8(Whh1 + g * HD + kk * 32 + qd * 8);
        }
    }

    // ---- wih0 frag table into LDS (bias0 folded into K-row 24 via x col24=1.0) ----
    for (int e = tid; e < 2048; e += NTH) {
        int tI2 = e >> 9, wv2 = (e >> 6) & 7, ln2 = e & 63;
        int qd2 = ln2 >> 4, nn2 = ln2 & 15;
        int g = tI2 * HD + wv2 * 16 + nn2;
        half8 f = z8;
        if (qd2 < 3) f = ldw8(Wih0 + g * NIN + qd2 * 8);
        else         f[0] = (_Float16)(bih0[g] + bhh0[g]);   // K-row 24
        *(half8*)&SM[WIH0_OFF + e * 8] = f;
    }

    __syncthreads();   // zero-init + wih0 table visible

    // ---- stage x chunk 0 (steps 0..3) into buf 0 ----
    if (tid < XCH * BT * 7) {
        int ti = tid / 112, r = tid % 112, b = r / 7, q = r % 7;
        half4v h;
        if (q < 6) {
            float4 v = *(const float4*)(x + (size_t)(b0 + b) * (TSTEPS * NIN) + ti * NIN + q * 4);
            h[0] = (_Float16)v.x; h[1] = (_Float16)v.y; h[2] = (_Float16)v.z; h[3] = (_Float16)v.w;
        } else {
            h[0] = (_Float16)1.f; h[1] = 0; h[2] = 0; h[3] = 0;   // col 24 = 1.0 (bias hook)
        }
        *(half4v*)&SM[XB_OFF + ti * XTS + b * XS + q * 4] = h;
    }

    float cs0[4] = {0.f, 0.f, 0.f, 0.f};
    float cs1[4] = {0.f, 0.f, 0.f, 0.f};

    // per-lane LDS element offsets (reused every step)
    const int aoff = nn * RS + qd * 8;         // A-frag base within a slot
    const int woff = (wv * 64 + ln) * 8;       // wih0 table stride per tI = 512*8

    // ====== fused loop: iteration t = L0 step t + L1 step t-1 ======
#pragma unroll 1
    for (int t = 0; t <= TSTEPS; ++t) {
        __syncthreads();

        // stage x chunk t/XCH + 1 (for steps t+4..t+7)
        if (t < TSTEPS && (t & (XCH - 1)) == 0 && t + XCH < TSTEPS) {
            const int c = (t >> 2) + 1, buf = c & 1;
            if (tid < XCH * BT * 7) {
                int ti = tid / 112, r = tid % 112, b = r / 7, q = r % 7;
                half4v h;
                if (q < 6) {
                    float4 v = *(const float4*)(x + (size_t)(b0 + b) * (TSTEPS * NIN)
                                                  + (size_t)(c * XCH + ti) * NIN + q * 4);
                    h[0] = (_Float16)v.x; h[1] = (_Float16)v.y;
                    h[2] = (_Float16)v.z; h[3] = (_Float16)v.w;
                } else {
                    h[0] = (_Float16)1.f; h[1] = 0; h[2] = 0; h[3] = 0;
                }
                *(half4v*)&SM[XB_OFF + buf * XBUF + ti * XTS + b * XS + q * 4] = h;
            }
        }

        const int rp = (t & 1) ^ 1;      // slot of h1_{t-1} (and h2_{t-1} write slot)

        // -------- layer 0, step t --------
        if (t < TSTEPS) {
            floatx4 acc[4];
            {
                const half8 ax = *(const half8*)&SM[XB_OFF + ((t >> 2) & 1) * XBUF
                                                    + (t & (XCH - 1)) * XTS + nn * XS + qd * 8];
#pragma unroll
                for (int tI = 0; tI < 4; ++tI) {
                    const half8 wf = *(const half8*)&SM[WIH0_OFF + tI * 4096 + woff];
                    floatx4 z = {0.f, 0.f, 0.f, 0.f};
                    acc[tI] = __builtin_amdgcn_mfma_f32_16x16x32_f16(ax, wf, z, 0, 0, 0);
                }
            }
            // stream h1_{t-1} frags: one ds_read feeds 4 MFMAs, one-ahead prefetch
            half8 f = *(const half8*)&SM[H1_OFF + rp * SLOT + aoff];
#pragma unroll
            for (int kk = 0; kk < 4; ++kk) {
                half8 fn;
                if (kk < 3) fn = *(const half8*)&SM[H1_OFF + rp * SLOT + aoff + (kk + 1) * 32];
#pragma unroll
                for (int tI = 0; tI < 4; ++tI)
                    acc[tI] = __builtin_amdgcn_mfma_f32_16x16x32_f16(f, whh0[tI][kk], acc[tI], 0, 0, 0);
                f = fn;
            }
            const int wp = t & 1;            // h1_t slot
#pragma unroll
            for (int r = 0; r < 4; ++r) {
                float iv = sigf(acc[0][r]);
                float fv = sigf(acc[1][r]);
                float gv = tanh_f(acc[2][r]);
                float ov = sigf(acc[3][r]);
                float cn = fv * cs0[r] + iv * gv;
                cs0[r] = cn;
                float hv = ov * tanh_f(cn);
                SM[H1_OFF + wp * SLOT + (qd * 4 + r) * RS + jc] = (_Float16)hv;
            }
        }

        // -------- layer 1, step t-1 --------
        if (t >= 1) {
            floatx4 acc[4];
#pragma unroll
            for (int tI = 0; tI < 4; ++tI) {
                floatx4 a = {bias1[tI], bias1[tI], bias1[tI], bias1[tI]};
                acc[tI] = a;
            }
            // stream 8 frags: kk 0..3 from h1_{t-1}, kk 4..7 from h2_{t-2}
            half8 f = *(const half8*)&SM[H1_OFF + rp * SLOT + aoff];
#pragma unroll
            for (int kk = 0; kk < 8; ++kk) {
                half8 fn;
                if (kk < 3)      fn = *(const half8*)&SM[H1_OFF + rp * SLOT + aoff + (kk + 1) * 32];
                else if (kk < 7) fn = *(const half8*)&SM[H2_OFF + (t & 1) * SLOT + aoff + (kk - 3) * 32];
#pragma unroll
                for (int tI = 0; tI < 4; ++tI)
                    acc[tI] = __builtin_amdgcn_mfma_f32_16x16x32_f16(f, w1[tI][kk], acc[tI], 0, 0, 0);
                f = fn;
            }
            const int wp = rp;               // h2_{t-1} slot
#pragma unroll
            for (int r = 0; r < 4; ++r) {
                float iv = sigf(acc[0][r]);
                float fv = sigf(acc[1][r]);
                float gv = tanh_f(acc[2][r]);
                float ov = sigf(acc[3][r]);
                float cn = fv * cs1[r] + iv * gv;
                cs1[r] = cn;
                float hv = ov * tanh_f(cn);
                SM[H2_OFF + wp * SLOT + (qd * 4 + r) * RS + jc] = (_Float16)hv;
            }
        }
    }
    __syncthreads();

    // ====== FC head: h2_127 is in H2 slot 1 ======
    {
        int b = tid >> 5, sub = tid & 31;
        const _Float16* hp = &SM[H2_OFF + SLOT + b * RS + sub * 4];
        const float4 wv4 = *(const float4*)(Wfc + sub * 4);
        float s = (float)hp[0] * wv4.x + (float)hp[1] * wv4.y
                + (float)hp[2] * wv4.z + (float)hp[3] * wv4.w;
        s += __shfl_down(s, 16, 32);
        s += __shfl_down(s, 8, 32);
        s += __shfl_down(s, 4, 32);
        s += __shfl_down(s, 2, 32);
        s += __shfl_down(s, 1, 32);
        if (sub == 0) out[b0 + b] = s + bfc[0];
    }
}

extern "C" void kernel_launch(void* const* d_in, const int* in_sizes, int n_in,
                              void* d_out, int out_size, void* d_ws, size_t ws_size,
                              hipStream_t stream) {
    const float* x    = (const float*)d_in[0];
    const float* Wih0 = (const float*)d_in[1];
    const float* Whh0 = (const float*)d_in[2];
    const float* bih0 = (const float*)d_in[3];
    const float* bhh0 = (const float*)d_in[4];
    const float* Wih1 = (const float*)d_in[5];
    const float* Whh1 = (const float*)d_in[6];
    const float* bih1 = (const float*)d_in[7];
    const float* bhh1 = (const float*)d_in[8];
    const float* Wfc  = (const float*)d_in[9];
    const float* bfc  = (const float*)d_in[10];
    float* out = (float*)d_out;

    lstm2_il<<<dim3(NBLK), dim3(NTH), 0, stream>>>(
        x, Wih0, Whh0, bih0, bhh0, Wih1, Whh1, bih1, bhh1, Wfc, bfc, out);
}

// Round 7
// 382.948 us; speedup vs baseline: 1.5483x; 1.0248x over previous
//
#include <hip/hip_runtime.h>

#define TSTEPS 128
#define NIN 24
#define HD 128
#define BT 16
#define NBLK 128     // 2048 / BT
#define NTH 512

// LDS geometry (units: _Float16 elements)
#define RS    136               // h-panel row stride (272 B: 16B-aligned)
#define SLOT  (BT*RS)           // 2176
#define XS    40                // x row stride (cols 0..23 x, col 24 = 1.0 bias hook, rest 0)
#define XTS   (BT*XS)           // 640 per timestep
#define XCH   4                 // steps per x chunk
#define XBUF  (XCH*XTS)         // 2560

#define WIH0_OFF 0                      // frag table: 4 tI * 512 lanes * 8 f16 = 16384 f16
#define H1_OFF   16384                  // 2 slots
#define H2_OFF   (H1_OFF + 2*SLOT)     // 20736
#define XB_OFF   (H2_OFF + 2*SLOT)     // 25088
#define SM_SIZE  (XB_OFF + 2*XBUF)     // 30208 f16 = 60416 B

typedef _Float16 half8  __attribute__((ext_vector_type(8)));
typedef _Float16 half4v __attribute__((ext_vector_type(4)));
typedef float    floatx4 __attribute__((ext_vector_type(4)));

// Pin a weight fragment into AGPRs (gfx950 unified file: MFMA reads B from
// VGPR or AGPR). Moves the 192 loop-invariant weight regs out of the arch
// half -> arch side holds only acc/frags/temps (~70), spill dies.
#define PIN_AGPR(v) asm volatile("" : "+a"(v))

__device__ __forceinline__ float sigf(float x) {
    return __builtin_amdgcn_rcpf(1.0f + __expf(-x));
}
__device__ __forceinline__ float tanh_f(float x) {
    return 1.0f - 2.0f * __builtin_amdgcn_rcpf(1.0f + __expf(2.0f * x));
}

__device__ __forceinline__ half8 ldw8(const float* p) {
    const float4* q = (const float4*)p;
    float4 a = q[0], b = q[1];
    half8 r;
    r[0] = (_Float16)a.x; r[1] = (_Float16)a.y; r[2] = (_Float16)a.z; r[3] = (_Float16)a.w;
    r[4] = (_Float16)b.x; r[5] = (_Float16)b.y; r[6] = (_Float16)b.z; r[7] = (_Float16)b.w;
    return r;
}

__global__ __launch_bounds__(NTH, 2)
void lstm2_il(const float* __restrict__ x,
              const float* __restrict__ Wih0, const float* __restrict__ Whh0,
              const float* __restrict__ bih0, const float* __restrict__ bhh0,
              const float* __restrict__ Wih1, const float* __restrict__ Whh1,
              const float* __restrict__ bih1, const float* __restrict__ bhh1,
              const float* __restrict__ Wfc,  const float* __restrict__ bfc,
              float* __restrict__ out)
{
    __shared__ __align__(16) _Float16 SM[SM_SIZE];

    const int tid = threadIdx.x;
    const int blk = blockIdx.x;
    const int wv  = tid >> 6;
    const int ln  = tid & 63;
    const int qd  = ln >> 4;
    const int nn  = ln & 15;
    const int b0  = blk * BT;
    const int jc  = wv * 16 + nn;       // this lane's h/gate column

    const half8 z8 = {0, 0, 0, 0, 0, 0, 0, 0};

    // ---- zero all LDS (h slots = initial h=0; x pad cols stay 0) ----
    for (int i = tid * 8; i < SM_SIZE; i += NTH * 8) *(half8*)&SM[i] = z8;

    // ---- resident weights, pinned to AGPRs: whh0 (64) + w1 (128) ----
    half8 whh0[4][4];
    half8 w1[4][8];
    float bias1[4];
#pragma unroll
    for (int tI = 0; tI < 4; ++tI) {
        int g = tI * HD + jc;
        bias1[tI] = bih1[g] + bhh1[g];
#pragma unroll
        for (int kk = 0; kk < 4; ++kk) {
            whh0[tI][kk] = ldw8(Whh0 + g * HD + kk * 32 + qd * 8);
            PIN_AGPR(whh0[tI][kk]);
            w1[tI][kk] = ldw8(Wih1 + g * HD + kk * 32 + qd * 8);
            PIN_AGPR(w1[tI][kk]);
            w1[tI][4 + kk] = ldw8(Whh1 + g * HD + kk * 32 + qd * 8);
            PIN_AGPR(w1[tI][4 + kk]);
        }
    }

    // ---- wih0 frag table into LDS (bias0 folded into K-row 24 via x col24=1.0) ----
    for (int e = tid; e < 2048; e += NTH) {
        int tI2 = e >> 9, wv2 = (e >> 6) & 7, ln2 = e & 63;
        int qd2 = ln2 >> 4, nn2 = ln2 & 15;
        int g = tI2 * HD + wv2 * 16 + nn2;
        half8 f = z8;
        if (qd2 < 3) f = ldw8(Wih0 + g * NIN + qd2 * 8);
        else         f[0] = (_Float16)(bih0[g] + bhh0[g]);   // K-row 24
        *(half8*)&SM[WIH0_OFF + e * 8] = f;
    }

    __syncthreads();   // zero-init + wih0 table visible

    // ---- stage x chunk 0 (steps 0..3) into buf 0 ----
    if (tid < XCH * BT * 7) {
        int ti = tid / 112, r = tid % 112, b = r / 7, q = r % 7;
        half4v h;
        if (q < 6) {
            float4 v = *(const float4*)(x + (size_t)(b0 + b) * (TSTEPS * NIN) + ti * NIN + q * 4);
            h[0] = (_Float16)v.x; h[1] = (_Float16)v.y; h[2] = (_Float16)v.z; h[3] = (_Float16)v.w;
        } else {
            h[0] = (_Float16)1.f; h[1] = 0; h[2] = 0; h[3] = 0;   // col 24 = 1.0 (bias hook)
        }
        *(half4v*)&SM[XB_OFF + ti * XTS + b * XS + q * 4] = h;
    }

    float cs0[4] = {0.f, 0.f, 0.f, 0.f};
    float cs1[4] = {0.f, 0.f, 0.f, 0.f};

    // per-lane LDS element offsets (reused every step)
    const int aoff = nn * RS + qd * 8;         // A-frag base within a slot
    const int woff = (wv * 64 + ln) * 8;       // wih0 table offset (per-tI stride 4096)

    // ====== fused loop: iteration t = L0 step t + L1 step t-1 ======
#pragma unroll 1
    for (int t = 0; t <= TSTEPS; ++t) {
        __syncthreads();

        // stage x chunk t/XCH + 1 (for steps t+4..t+7)
        if (t < TSTEPS && (t & (XCH - 1)) == 0 && t + XCH < TSTEPS) {
            const int c = (t >> 2) + 1, buf = c & 1;
            if (tid < XCH * BT * 7) {
                int ti = tid / 112, r = tid % 112, b = r / 7, q = r % 7;
                half4v h;
                if (q < 6) {
                    float4 v = *(const float4*)(x + (size_t)(b0 + b) * (TSTEPS * NIN)
                                                  + (size_t)(c * XCH + ti) * NIN + q * 4);
                    h[0] = (_Float16)v.x; h[1] = (_Float16)v.y;
                    h[2] = (_Float16)v.z; h[3] = (_Float16)v.w;
                } else {
                    h[0] = (_Float16)1.f; h[1] = 0; h[2] = 0; h[3] = 0;
                }
                *(half4v*)&SM[XB_OFF + buf * XBUF + ti * XTS + b * XS + q * 4] = h;
            }
        }

        const int rp = (t & 1) ^ 1;      // slot of h1_{t-1} (and h2_{t-1} write slot)

        // -------- layer 0, step t --------
        if (t < TSTEPS) {
            floatx4 acc[4];
            {
                const half8 ax = *(const half8*)&SM[XB_OFF + ((t >> 2) & 1) * XBUF
                                                    + (t & (XCH - 1)) * XTS + nn * XS + qd * 8];
#pragma unroll
                for (int tI = 0; tI < 4; ++tI) {
                    const half8 wf = *(const half8*)&SM[WIH0_OFF + tI * 4096 + woff];
                    floatx4 z = {0.f, 0.f, 0.f, 0.f};
                    acc[tI] = __builtin_amdgcn_mfma_f32_16x16x32_f16(ax, wf, z, 0, 0, 0);
                }
            }
            // stream h1_{t-1} frags: one ds_read feeds 4 MFMAs, then dies
#pragma unroll
            for (int kk = 0; kk < 4; ++kk) {
                const half8 f = *(const half8*)&SM[H1_OFF + rp * SLOT + aoff + kk * 32];
#pragma unroll
                for (int tI = 0; tI < 4; ++tI)
                    acc[tI] = __builtin_amdgcn_mfma_f32_16x16x32_f16(f, whh0[tI][kk], acc[tI], 0, 0, 0);
            }
            const int wp = t & 1;            // h1_t slot
#pragma unroll
            for (int r = 0; r < 4; ++r) {
                float iv = sigf(acc[0][r]);
                float fv = sigf(acc[1][r]);
                float gv = tanh_f(acc[2][r]);
                float ov = sigf(acc[3][r]);
                float cn = fv * cs0[r] + iv * gv;
                cs0[r] = cn;
                float hv = ov * tanh_f(cn);
                SM[H1_OFF + wp * SLOT + (qd * 4 + r) * RS + jc] = (_Float16)hv;
            }
        }

        // -------- layer 1, step t-1 --------
        if (t >= 1) {
            floatx4 acc[4];
#pragma unroll
            for (int tI = 0; tI < 4; ++tI) {
                floatx4 a = {bias1[tI], bias1[tI], bias1[tI], bias1[tI]};
                acc[tI] = a;
            }
            // stream 8 frags: kk 0..3 from h1_{t-1}, kk 4..7 from h2_{t-2}
#pragma unroll
            for (int kk = 0; kk < 8; ++kk) {
                const half8 f = (kk < 4)
                    ? *(const half8*)&SM[H1_OFF + rp * SLOT + aoff + kk * 32]
                    : *(const half8*)&SM[H2_OFF + (t & 1) * SLOT + aoff + (kk - 4) * 32];
#pragma unroll
                for (int tI = 0; tI < 4; ++tI)
                    acc[tI] = __builtin_amdgcn_mfma_f32_16x16x32_f16(f, w1[tI][kk], acc[tI], 0, 0, 0);
            }
            const int wp = rp;               // h2_{t-1} slot
#pragma unroll
            for (int r = 0; r < 4; ++r) {
                float iv = sigf(acc[0][r]);
                float fv = sigf(acc[1][r]);
                float gv = tanh_f(acc[2][r]);
                float ov = sigf(acc[3][r]);
                float cn = fv * cs1[r] + iv * gv;
                cs1[r] = cn;
                float hv = ov * tanh_f(cn);
                SM[H2_OFF + wp * SLOT + (qd * 4 + r) * RS + jc] = (_Float16)hv;
            }
        }
    }
    __syncthreads();

    // ====== FC head: h2_127 is in H2 slot 1 ======
    {
        int b = tid >> 5, sub = tid & 31;
        const _Float16* hp = &SM[H2_OFF + SLOT + b * RS + sub * 4];
        const float4 wv4 = *(const float4*)(Wfc + sub * 4);
        float s = (float)hp[0] * wv4.x + (float)hp[1] * wv4.y
                + (float)hp[2] * wv4.z + (float)hp[3] * wv4.w;
        s += __shfl_down(s, 16, 32);
        s += __shfl_down(s, 8, 32);
        s += __shfl_down(s, 4, 32);
        s += __shfl_down(s, 2, 32);
        s += __shfl_down(s, 1, 32);
        if (sub == 0) out[b0 + b] = s + bfc[0];
    }
}

extern "C" void kernel_launch(void* const* d_in, const int* in_sizes, int n_in,
                              void* d_out, int out_size, void* d_ws, size_t ws_size,
                              hipStream_t stream) {
    const float* x    = (const float*)d_in[0];
    const float* Wih0 = (const float*)d_in[1];
    const float* Whh0 = (const float*)d_in[2];
    const float* bih0 = (const float*)d_in[3];
    const float* bhh0 = (const float*)d_in[4];
    const float* Wih1 = (const float*)d_in[5];
    const float* Whh1 = (const float*)d_in[6];
    const float* bih1 = (const float*)d_in[7];
    const float* bhh1 = (const float*)d_in[8];
    const float* Wfc  = (const float*)d_in[9];
    const float* bfc  = (const float*)d_in[10];
    float* out = (float*)d_out;

    lstm2_il<<<dim3(NBLK), dim3(NTH), 0, stream>>>(
        x, Wih0, Whh0, bih0, bhh0, Wih1, Whh1, bih1, bhh1, Wfc, bfc, out);
}